// Round 1
// baseline (511.303 us; speedup 1.0000x reference)
//
#include <hip/hip_runtime.h>
#include <math.h>

#define N_TOK   32768
#define K_CODES 8192
#define E_DIM   32
#define NCHUNK  8
#define KCHUNK  (K_CODES / NCHUNK)   // 1024
#define TILE    512
#define BLK     256
#define TPB     (BLK * 2)            // tokens per block in screen
#define TAU     1e-3f

// d_out element offsets (float32 buffer)
#define OUT_IDX  1048576
#define OUT_QL   1081344
#define OUT_EL   1081345

// ws element offsets (4B units)
#define WS_EMBN   0         // 262144 f32
#define WS_PBEST  262144    // 8*32768 f32
#define WS_PSEC   524288    // 8*32768 f32
#define WS_PIDX   786432    // 8*32768 i32
#define WS_FIDX   1048576   // 32768 i32
#define WS_FCNT   1081344   // 1 i32 (padded)
#define WS_FLIST  1081376   // 32768 i32
#define WS_LPART  1114144   // 512 f32 (wave loss partials)

__global__ __launch_bounds__(BLK) void norm_emb_kernel(
    const float* __restrict__ emb, float* __restrict__ embn)
{
  const int r = blockIdx.x * BLK + threadIdx.x;
  const float4* p = (const float4*)(emb + r * E_DIM);
  float4 v[8];
  float s = 0.f;
#pragma unroll
  for (int q = 0; q < 8; ++q) {
    v[q] = p[q];
    s += v[q].x * v[q].x + v[q].y * v[q].y + v[q].z * v[q].z + v[q].w * v[q].w;
  }
  const float rn = 1.f / sqrtf(s + 1e-12f);
  float4* o = (float4*)(embn + r * E_DIM);
#pragma unroll
  for (int q = 0; q < 8; ++q) {
    float4 w = v[q];
    w.x *= rn; w.y *= rn; w.z *= rn; w.w *= rn;
    o[q] = w;
  }
}

// grid: (N_TOK/TPB = 64, NCHUNK = 8), block: 256. Each thread owns 2 tokens.
__global__ __launch_bounds__(BLK) void screen_kernel(
    const float* __restrict__ hs, const float* __restrict__ embn,
    float* __restrict__ pbest, float* __restrict__ psec, int* __restrict__ pidx)
{
  __shared__ float4 lds4[TILE * E_DIM / 4];   // 64 KB
  const int tid = threadIdx.x;
  const int t0 = blockIdx.x * TPB + tid;
  const int t1 = t0 + BLK;
  const int chunk = blockIdx.y;

  // load + L2-normalize the two tokens (f32)
  float4 z0[8], z1[8];
  {
    const float4* p0 = (const float4*)(hs + t0 * E_DIM);
    const float4* p1 = (const float4*)(hs + t1 * E_DIM);
    float s0 = 0.f, s1 = 0.f;
#pragma unroll
    for (int q = 0; q < 8; ++q) {
      z0[q] = p0[q]; z1[q] = p1[q];
      s0 += z0[q].x * z0[q].x + z0[q].y * z0[q].y + z0[q].z * z0[q].z + z0[q].w * z0[q].w;
      s1 += z1[q].x * z1[q].x + z1[q].y * z1[q].y + z1[q].z * z1[q].z + z1[q].w * z1[q].w;
    }
    const float r0 = 1.f / sqrtf(s0 + 1e-12f);
    const float r1 = 1.f / sqrtf(s1 + 1e-12f);
#pragma unroll
    for (int q = 0; q < 8; ++q) {
      z0[q].x *= r0; z0[q].y *= r0; z0[q].z *= r0; z0[q].w *= r0;
      z1[q].x *= r1; z1[q].y *= r1; z1[q].z *= r1; z1[q].w *= r1;
    }
  }

  float best0 = -3e38f, sec0 = -3e38f, best1 = -3e38f, sec1 = -3e38f;
  int idx0 = 0, idx1 = 0;

  for (int tb = 0; tb < KCHUNK; tb += TILE) {
    const int cbase = chunk * KCHUNK + tb;
    __syncthreads();   // protect previous tile's readers
    const float4* src = (const float4*)(embn + cbase * E_DIM);
#pragma unroll
    for (int it = 0; it < (TILE * E_DIM / 4) / BLK; ++it) {
      const int f = tid + it * BLK;
      lds4[f] = src[f];
    }
    __syncthreads();

#pragma unroll 2
    for (int c = 0; c < TILE; ++c) {
      float ax0 = 0.f, ay0 = 0.f, az0 = 0.f, aw0 = 0.f;
      float ax1 = 0.f, ay1 = 0.f, az1 = 0.f, aw1 = 0.f;
#pragma unroll
      for (int q = 0; q < 8; ++q) {
        const float4 e = lds4[c * 8 + q];   // uniform address -> broadcast
        ax0 = fmaf(z0[q].x, e.x, ax0);
        ay0 = fmaf(z0[q].y, e.y, ay0);
        az0 = fmaf(z0[q].z, e.z, az0);
        aw0 = fmaf(z0[q].w, e.w, aw0);
        ax1 = fmaf(z1[q].x, e.x, ax1);
        ay1 = fmaf(z1[q].y, e.y, ay1);
        az1 = fmaf(z1[q].z, e.z, az1);
        aw1 = fmaf(z1[q].w, e.w, aw1);
      }
      const float d0 = (ax0 + ay0) + (az0 + aw0);
      const float d1 = (ax1 + ay1) + (az1 + aw1);
      const int code = cbase + c;
      float m;
      m = fminf(best0, d0); sec0 = fmaxf(sec0, m);
      if (d0 > best0) { best0 = d0; idx0 = code; }
      m = fminf(best1, d1); sec1 = fmaxf(sec1, m);
      if (d1 > best1) { best1 = d1; idx1 = code; }
    }
  }

  const int b = chunk * N_TOK;
  pbest[b + t0] = best0; psec[b + t0] = sec0; pidx[b + t0] = idx0;
  pbest[b + t1] = best1; psec[b + t1] = sec1; pidx[b + t1] = idx1;
}

__global__ __launch_bounds__(BLK) void merge_kernel(
    const float* __restrict__ pbest, const float* __restrict__ psec,
    const int* __restrict__ pidx, int* __restrict__ fidx,
    int* __restrict__ flagcnt, int* __restrict__ flaglist)
{
  const int t = blockIdx.x * BLK + threadIdx.x;
  float best = -3e38f, sec = -3e38f;
  int idx = 0;
#pragma unroll
  for (int ch = 0; ch < NCHUNK; ++ch) {
    const float b = pbest[ch * N_TOK + t];
    const float s = psec[ch * N_TOK + t];
    const int i = pidx[ch * N_TOK + t];
    if (b > best) { sec = fmaxf(best, s); best = b; idx = i; }
    else          { sec = fmaxf(sec, b); }
  }
  fidx[t] = idx;
  if (best - sec < TAU) {
    const int p = atomicAdd(flagcnt, 1);
    flaglist[p] = t;
  }
}

// exact f64 rescan for near-tie tokens; one block per flagged token
__global__ __launch_bounds__(256) void recheck_kernel(
    const float* __restrict__ hs, const float* __restrict__ emb,
    const int* __restrict__ flagcnt, const int* __restrict__ flaglist,
    int* __restrict__ fidx)
{
  __shared__ double rv[256];
  __shared__ int ri[256];
  const int tid = threadIdx.x;
  const int nflag = *flagcnt;
  for (int f = blockIdx.x; f < nflag; f += gridDim.x) {
    const int t = flaglist[f];
    // token normalize in f64 (redundant per thread; cheap)
    double z[E_DIM];
    double s = 0.0;
    const float* hp = hs + t * E_DIM;
#pragma unroll
    for (int j = 0; j < E_DIM; ++j) { z[j] = (double)hp[j]; s += z[j] * z[j]; }
    const double rz = 1.0 / sqrt(s + 1e-12);
#pragma unroll
    for (int j = 0; j < E_DIM; ++j) z[j] *= rz;

    double best = -3e300;
    int bidx = 0;
    for (int c = tid; c < K_CODES; c += 256) {
      const float* ep = emb + c * E_DIM;
      double dot = 0.0, n2 = 0.0;
#pragma unroll
      for (int j = 0; j < E_DIM; ++j) {
        const double e = (double)ep[j];
        dot = fma(e, z[j], dot);
        n2 = fma(e, e, n2);
      }
      const double val = dot * (1.0 / sqrt(n2 + 1e-12));
      if (val > best) { best = val; bidx = c; }   // strict > keeps smallest c
    }
    __syncthreads();
    rv[tid] = best; ri[tid] = bidx;
    __syncthreads();
    for (int sr = 128; sr > 0; sr >>= 1) {
      if (tid < sr) {
        if (rv[tid + sr] > rv[tid] ||
            (rv[tid + sr] == rv[tid] && ri[tid + sr] < ri[tid])) {
          rv[tid] = rv[tid + sr]; ri[tid] = ri[tid + sr];
        }
      }
      __syncthreads();
    }
    if (tid == 0) fidx[t] = ri[0];
  }
}

__global__ __launch_bounds__(BLK) void finalize_kernel(
    const float* __restrict__ hs, const float* __restrict__ emb,
    const int* __restrict__ fidx, float* __restrict__ out,
    float* __restrict__ lpart)
{
  const int t = blockIdx.x * BLK + threadIdx.x;
  const int idx = fidx[t];
  const float4* ep = (const float4*)(emb + idx * E_DIM);
  const float4* hp = (const float4*)(hs + t * E_DIM);
  float4 e[8], h[8];
  float se = 0.f, sh = 0.f;
#pragma unroll
  for (int q = 0; q < 8; ++q) {
    e[q] = ep[q]; h[q] = hp[q];
    se += e[q].x * e[q].x + e[q].y * e[q].y + e[q].z * e[q].z + e[q].w * e[q].w;
    sh += h[q].x * h[q].x + h[q].y * h[q].y + h[q].z * h[q].z + h[q].w * h[q].w;
  }
  const float re = 1.f / sqrtf(se + 1e-12f);
  const float rh = 1.f / sqrtf(sh + 1e-12f);
  float4* zo = (float4*)(out + t * E_DIM);
  float err = 0.f;
#pragma unroll
  for (int q = 0; q < 8; ++q) {
    float4 zq, hn;
    zq.x = e[q].x * re; zq.y = e[q].y * re; zq.z = e[q].z * re; zq.w = e[q].w * re;
    hn.x = h[q].x * rh; hn.y = h[q].y * rh; hn.z = h[q].z * rh; hn.w = h[q].w * rh;
    float dx = zq.x - hn.x, dy = zq.y - hn.y, dz = zq.z - hn.z, dw = zq.w - hn.w;
    err += dx * dx + dy * dy + dz * dz + dw * dw;
    zo[q] = zq;
  }
  out[OUT_IDX + t] = (float)idx;
  // wave reduce err -> per-wave partial (deterministic)
#pragma unroll
  for (int o = 32; o > 0; o >>= 1) err += __shfl_down(err, o);
  if ((threadIdx.x & 63) == 0) {
    const int wave = t >> 6;   // 0..511
    lpart[wave] = err;
  }
}

__global__ __launch_bounds__(256) void loss_kernel(
    const float* __restrict__ lpart, float* __restrict__ out)
{
  const int tid = threadIdx.x;
  float a = lpart[tid] + lpart[tid + 256];
#pragma unroll
  for (int o = 32; o > 0; o >>= 1) a += __shfl_down(a, o);
  __shared__ float w[4];
  if ((tid & 63) == 0) w[tid >> 6] = a;
  __syncthreads();
  if (tid == 0) {
    const float tot = (w[0] + w[1]) + (w[2] + w[3]);
    const float c = tot * (1.0f / 1048576.0f);
    out[OUT_QL] = c;
    out[OUT_EL] = c;
  }
}

extern "C" void kernel_launch(void* const* d_in, const int* in_sizes, int n_in,
                              void* d_out, int out_size, void* d_ws, size_t ws_size,
                              hipStream_t stream) {
  (void)in_sizes; (void)n_in; (void)out_size; (void)ws_size;
  const float* hs  = (const float*)d_in[0];
  const float* emb = (const float*)d_in[1];
  float* out = (float*)d_out;
  float* ws  = (float*)d_ws;

  float* embn    = ws + WS_EMBN;
  float* pbest   = ws + WS_PBEST;
  float* psec    = ws + WS_PSEC;
  int*   pidx    = (int*)(ws + WS_PIDX);
  int*   fidx    = (int*)(ws + WS_FIDX);
  int*   flagcnt = (int*)(ws + WS_FCNT);
  int*   flist   = (int*)(ws + WS_FLIST);
  float* lpart   = ws + WS_LPART;

  hipMemsetAsync(flagcnt, 0, sizeof(int), stream);

  norm_emb_kernel<<<dim3(K_CODES / BLK), BLK, 0, stream>>>(emb, embn);
  screen_kernel<<<dim3(N_TOK / TPB, NCHUNK), BLK, 0, stream>>>(hs, embn, pbest, psec, pidx);
  merge_kernel<<<dim3(N_TOK / BLK), BLK, 0, stream>>>(pbest, psec, pidx, fidx, flagcnt, flist);
  recheck_kernel<<<dim3(128), 256, 0, stream>>>(hs, emb, flagcnt, flist, fidx);
  finalize_kernel<<<dim3(N_TOK / BLK), BLK, 0, stream>>>(hs, emb, fidx, out, lpart);
  loss_kernel<<<dim3(1), 256, 0, stream>>>(lpart, out);
}

// Round 2
// 299.614 us; speedup vs baseline: 1.7065x; 1.7065x over previous
//
#include <hip/hip_runtime.h>
#include <math.h>

#define N_TOK   32768
#define K_CODES 8192
#define E_DIM   32
#define BLK     256
#define TAU     1e-3f
#define NTILE_T (N_TOK / 16)     // 2048 token tiles
#define NTILE_C (K_CODES / 16)   // 512 code tiles

// d_out element offsets (float32 buffer)
#define OUT_IDX  1048576
#define OUT_QL   1081344
#define OUT_EL   1081345

// ws byte offsets
#define WSB_BHI   0          // 262144 ushort + 1024 pad = 526336 B
#define WSB_BLO   526336     // 526336 B
#define WSB_FIDX  1052672    // 32768 i32 = 131072 B
#define WSB_FCNT  1183744    // 128 B
#define WSB_FLIST 1183872    // 131072 B
#define WSB_LPART 1314944    // 512 f32

typedef __attribute__((ext_vector_type(8))) short bf16x8;
typedef __attribute__((ext_vector_type(4))) float f32x4;

__device__ inline unsigned short bf16_rne(float x) {
  unsigned u = __builtin_bit_cast(unsigned, x);
  unsigned r = u + 0x7FFFu + ((u >> 16) & 1u);
  return (unsigned short)(r >> 16);
}
__device__ inline float bf16_to_f32(unsigned short h) {
  return __builtin_bit_cast(float, (unsigned)h << 16);
}

// one thread per code: normalize, split to bf16 hi/lo, store MFMA-B-packed:
// dst[(tile*4+g)*16 + row] (short8) = embn[tile*16+row][g*8 .. g*8+7]
__global__ __launch_bounds__(BLK) void prep_emb_kernel(
    const float* __restrict__ emb, bf16x8* __restrict__ bhi, bf16x8* __restrict__ blo)
{
  const int c = blockIdx.x * BLK + threadIdx.x;
  float z[E_DIM];
  const float4* p = (const float4*)(emb + c * E_DIM);
  float s = 0.f;
#pragma unroll
  for (int q = 0; q < 8; ++q) {
    float4 v = p[q];
    ((float4*)z)[q] = v;
    s += v.x * v.x + v.y * v.y + v.z * v.z + v.w * v.w;
  }
  const float rn = 1.f / sqrtf(s + 1e-12f);
  const int tile = c >> 4, row = c & 15;
#pragma unroll
  for (int g = 0; g < 4; ++g) {
    bf16x8 h8, l8;
#pragma unroll
    for (int j = 0; j < 8; ++j) {
      const float zn = z[g * 8 + j] * rn;
      const unsigned short h = bf16_rne(zn);
      h8[j] = (short)h;
      l8[j] = (short)bf16_rne(zn - bf16_to_f32(h));
    }
    const int dst = (tile * 4 + g) * 16 + row;
    bhi[dst] = h8;
    blo[dst] = l8;
  }
}

// grid: 512 blocks x 256 thr (4 waves); wave = one 16-token tile, loops all codes.
__global__ __launch_bounds__(BLK) void screen_kernel(
    const float* __restrict__ hs, const bf16x8* __restrict__ Bh,
    const bf16x8* __restrict__ Bl, int* __restrict__ fidx,
    int* __restrict__ flagcnt, int* __restrict__ flaglist)
{
  const int lane = threadIdx.x & 63;
  const int grp = lane >> 4, row = lane & 15;
  const int tile = blockIdx.x * 4 + (threadIdx.x >> 6);

  // A fragment: lane holds z[tile*16+row][grp*8 .. grp*8+7], normalized, hi/lo
  bf16x8 ahi, alo;
  {
    const float* ap = hs + (tile * 16 + row) * E_DIM + grp * 8;
    float a[8];
    ((float4*)a)[0] = ((const float4*)ap)[0];
    ((float4*)a)[1] = ((const float4*)ap)[1];
    float ps = 0.f;
#pragma unroll
    for (int j = 0; j < 8; ++j) ps = fmaf(a[j], a[j], ps);
    ps += __shfl_xor(ps, 16, 64);
    ps += __shfl_xor(ps, 32, 64);
    const float rn = 1.f / sqrtf(ps + 1e-12f);
#pragma unroll
    for (int j = 0; j < 8; ++j) {
      const float zn = a[j] * rn;
      const unsigned short h = bf16_rne(zn);
      ahi[j] = (short)h;
      alo[j] = (short)bf16_rne(zn - bf16_to_f32(h));
    }
  }

  float best[4], sec[4];
  int idx[4];
#pragma unroll
  for (int r = 0; r < 4; ++r) { best[r] = -3e38f; sec[r] = -3e38f; idx[r] = 0; }

  const int loff = grp * 16 + row;
  const f32x4 z4 = {0.f, 0.f, 0.f, 0.f};

#define UPDATE(ACC, CODE)                                                 \
  {                                                                       \
    _Pragma("unroll")                                                     \
    for (int r = 0; r < 4; ++r) {                                         \
      const float d = (ACC)[r];                                           \
      sec[r] = __builtin_amdgcn_fmed3f(best[r], sec[r], d);               \
      if (d > best[r]) { best[r] = d; idx[r] = (CODE); }                  \
    }                                                                     \
  }

  bf16x8 h0 = Bh[loff],      l0 = Bl[loff];
  bf16x8 h1 = Bh[64 + loff], l1 = Bl[64 + loff];
  for (int ct = 0; ct < NTILE_C; ct += 2) {
    const bf16x8 ch0 = h0, cl0 = l0, ch1 = h1, cl1 = l1;
    const int nx = (ct + 2) * 64 + loff;   // pad tiles make this always safe
    h0 = Bh[nx];      l0 = Bl[nx];
    h1 = Bh[nx + 64]; l1 = Bl[nx + 64];

    f32x4 acc = __builtin_amdgcn_mfma_f32_16x16x32_bf16(ahi, ch0, z4, 0, 0, 0);
    acc = __builtin_amdgcn_mfma_f32_16x16x32_bf16(ahi, cl0, acc, 0, 0, 0);
    acc = __builtin_amdgcn_mfma_f32_16x16x32_bf16(alo, ch0, acc, 0, 0, 0);
    const int code0 = ct * 16 + row;
    UPDATE(acc, code0)

    f32x4 acc2 = __builtin_amdgcn_mfma_f32_16x16x32_bf16(ahi, ch1, z4, 0, 0, 0);
    acc2 = __builtin_amdgcn_mfma_f32_16x16x32_bf16(ahi, cl1, acc2, 0, 0, 0);
    acc2 = __builtin_amdgcn_mfma_f32_16x16x32_bf16(alo, ch1, acc2, 0, 0, 0);
    UPDATE(acc2, code0 + 16)
  }
#undef UPDATE

  // cross-lane merge over the 16 code-columns (lanes sharing lane>>4)
#pragma unroll
  for (int w = 1; w < 16; w <<= 1) {
#pragma unroll
    for (int r = 0; r < 4; ++r) {
      const float ob = __shfl_xor(best[r], w, 64);
      const float os = __shfl_xor(sec[r], w, 64);
      const int   oi = __shfl_xor(idx[r], w, 64);
      const float nb = fmaxf(best[r], ob);
      const float ns = fmaxf(fminf(best[r], ob), fmaxf(sec[r], os));
      if (ob > best[r]) idx[r] = oi;
      best[r] = nb; sec[r] = ns;
    }
  }

  if (row == 0) {
#pragma unroll
    for (int r = 0; r < 4; ++r) {
      const int tok = tile * 16 + grp * 4 + r;
      fidx[tok] = idx[r];
      if (best[r] - sec[r] < TAU) {
        const int p = atomicAdd(flagcnt, 1);
        flaglist[p] = tok;
      }
    }
  }
}

// exact f64 rescan (incl. the eps norm term) for near-tie tokens
__global__ __launch_bounds__(256) void recheck_kernel(
    const float* __restrict__ hs, const float* __restrict__ emb,
    const int* __restrict__ flagcnt, const int* __restrict__ flaglist,
    int* __restrict__ fidx)
{
  __shared__ double rv[256];
  __shared__ int ri[256];
  const int tid = threadIdx.x;
  const int nflag = *flagcnt;
  for (int f = blockIdx.x; f < nflag; f += gridDim.x) {
    const int t = flaglist[f];
    double z[E_DIM];
    double s = 0.0;
    const float* hp = hs + t * E_DIM;
#pragma unroll
    for (int j = 0; j < E_DIM; ++j) { z[j] = (double)hp[j]; s += z[j] * z[j]; }
    const double rz = 1.0 / sqrt(s + 1e-12);
#pragma unroll
    for (int j = 0; j < E_DIM; ++j) z[j] *= rz;

    double bobj = 1e300;
    int bidx = 0x7fffffff;
    for (int c = tid; c < K_CODES; c += 256) {
      const float* ep = emb + c * E_DIM;
      double dot = 0.0, n2 = 0.0;
#pragma unroll
      for (int j = 0; j < E_DIM; ++j) {
        const double e = (double)ep[j];
        dot = fma(e, z[j], dot);
        n2 = fma(e, e, n2);
      }
      const double obj = n2 / (n2 + 1e-12) - 2.0 * (dot / sqrt(n2 + 1e-12));
      if (obj < bobj) { bobj = obj; bidx = c; }   // strict < keeps smallest c
    }
    __syncthreads();
    rv[tid] = bobj; ri[tid] = bidx;
    __syncthreads();
    for (int sr = 128; sr > 0; sr >>= 1) {
      if (tid < sr) {
        if (rv[tid + sr] < rv[tid] ||
            (rv[tid + sr] == rv[tid] && ri[tid + sr] < ri[tid])) {
          rv[tid] = rv[tid + sr]; ri[tid] = ri[tid + sr];
        }
      }
      __syncthreads();
    }
    if (tid == 0) fidx[t] = ri[0];
    __syncthreads();
  }
}

__global__ __launch_bounds__(BLK) void finalize_kernel(
    const float* __restrict__ hs, const float* __restrict__ emb,
    const int* __restrict__ fidx, float* __restrict__ out,
    float* __restrict__ lpart)
{
  const int t = blockIdx.x * BLK + threadIdx.x;
  const int idx = fidx[t];
  const float4* ep = (const float4*)(emb + idx * E_DIM);
  const float4* hp = (const float4*)(hs + t * E_DIM);
  float4 e[8], h[8];
  float se = 0.f, sh = 0.f;
#pragma unroll
  for (int q = 0; q < 8; ++q) {
    e[q] = ep[q]; h[q] = hp[q];
    se += e[q].x * e[q].x + e[q].y * e[q].y + e[q].z * e[q].z + e[q].w * e[q].w;
    sh += h[q].x * h[q].x + h[q].y * h[q].y + h[q].z * h[q].z + h[q].w * h[q].w;
  }
  const float re = 1.f / sqrtf(se + 1e-12f);
  const float rh = 1.f / sqrtf(sh + 1e-12f);
  float4* zo = (float4*)(out + t * E_DIM);
  float err = 0.f;
#pragma unroll
  for (int q = 0; q < 8; ++q) {
    float4 zq, hn;
    zq.x = e[q].x * re; zq.y = e[q].y * re; zq.z = e[q].z * re; zq.w = e[q].w * re;
    hn.x = h[q].x * rh; hn.y = h[q].y * rh; hn.z = h[q].z * rh; hn.w = h[q].w * rh;
    float dx = zq.x - hn.x, dy = zq.y - hn.y, dz = zq.z - hn.z, dw = zq.w - hn.w;
    err += dx * dx + dy * dy + dz * dz + dw * dw;
    zo[q] = zq;
  }
  out[OUT_IDX + t] = (float)idx;
#pragma unroll
  for (int o = 32; o > 0; o >>= 1) err += __shfl_down(err, o);
  if ((threadIdx.x & 63) == 0) lpart[t >> 6] = err;
}

__global__ __launch_bounds__(256) void loss_kernel(
    const float* __restrict__ lpart, float* __restrict__ out)
{
  const int tid = threadIdx.x;
  float a = lpart[tid] + lpart[tid + 256];
#pragma unroll
  for (int o = 32; o > 0; o >>= 1) a += __shfl_down(a, o);
  __shared__ float w[4];
  if ((tid & 63) == 0) w[tid >> 6] = a;
  __syncthreads();
  if (tid == 0) {
    const float tot = (w[0] + w[1]) + (w[2] + w[3]);
    const float c = tot * (1.0f / 1048576.0f);
    out[OUT_QL] = c;
    out[OUT_EL] = c;
  }
}

extern "C" void kernel_launch(void* const* d_in, const int* in_sizes, int n_in,
                              void* d_out, int out_size, void* d_ws, size_t ws_size,
                              hipStream_t stream) {
  (void)in_sizes; (void)n_in; (void)out_size; (void)ws_size;
  const float* hs  = (const float*)d_in[0];
  const float* emb = (const float*)d_in[1];
  float* out = (float*)d_out;
  char* wsb = (char*)d_ws;

  bf16x8* bhi    = (bf16x8*)(wsb + WSB_BHI);
  bf16x8* blo    = (bf16x8*)(wsb + WSB_BLO);
  int*    fidx   = (int*)(wsb + WSB_FIDX);
  int*    flagcnt= (int*)(wsb + WSB_FCNT);
  int*    flist  = (int*)(wsb + WSB_FLIST);
  float*  lpart  = (float*)(wsb + WSB_LPART);

  hipMemsetAsync(flagcnt, 0, sizeof(int), stream);

  prep_emb_kernel<<<dim3(K_CODES / BLK), BLK, 0, stream>>>(emb, bhi, blo);
  screen_kernel<<<dim3(NTILE_T / 4), BLK, 0, stream>>>(hs, bhi, blo, fidx, flagcnt, flist);
  recheck_kernel<<<dim3(256), 256, 0, stream>>>(hs, emb, flagcnt, flist, fidx);
  finalize_kernel<<<dim3(N_TOK / BLK), BLK, 0, stream>>>(hs, emb, fidx, out, lpart);
  loss_kernel<<<dim3(1), 256, 0, stream>>>(lpart, out);
}

// Round 4
// 204.609 us; speedup vs baseline: 2.4989x; 1.4643x over previous
//
#include <hip/hip_runtime.h>
#include <math.h>

#define N_TOK   32768
#define K_CODES 8192
#define E_DIM   32
#define BLK     256
#define NCHUNK  8
#define TPC     64          // code tiles per chunk (8192/8/16)
#define TT      4           // token tiles per wave
#define TAU     1e-3f       // proven in R2

// d_out element offsets (float32 buffer)
#define OUT_IDX  1048576
#define OUT_QL   1081344
#define OUT_EL   1081345

// ws byte offsets
#define WSB_BPK    0         // 514 tiles * 2048 B (hi 1KB + lo 1KB interleaved)
#define WSB_PBEST  1052672   // 8*32768 f32
#define WSB_PSEC   2101248   // 8*32768 f32
#define WSB_PIDX   3149824   // 8*32768 u16
#define WSB_FIDX   3674112   // 32768 i32
#define WSB_FCNT   3805184   // 128 B
#define WSB_FLIST  3805312   // 32768 i32
#define WSB_LPART  3936384   // 512 f32

typedef __attribute__((ext_vector_type(8))) short bf16x8;
typedef __attribute__((ext_vector_type(4))) float f32x4;

__device__ inline unsigned short bf16_rne(float x) {
  unsigned u = __builtin_bit_cast(unsigned, x);
  unsigned r = u + 0x7FFFu + ((u >> 16) & 1u);
  return (unsigned short)(r >> 16);
}
__device__ inline float bf16_to_f32(unsigned short h) {
  return __builtin_bit_cast(float, (unsigned)h << 16);
}

// one thread per code: normalize, bf16 hi/lo split, store MFMA-B-packed:
// tile t bytes [t*2048, +1024) = hi frag, [+1024, +2048) = lo frag;
// frag byte (g*16+coderow)*16 = code (t*16+coderow), dims g*8..+8
__global__ __launch_bounds__(BLK) void prep_emb_kernel(
    const float* __restrict__ emb, char* __restrict__ Bpk)
{
  const int c = blockIdx.x * BLK + threadIdx.x;
  float z[E_DIM];
  const float4* p = (const float4*)(emb + c * E_DIM);
  float s = 0.f;
#pragma unroll
  for (int q = 0; q < 8; ++q) {
    float4 v = p[q];
    ((float4*)z)[q] = v;
    s += v.x * v.x + v.y * v.y + v.z * v.z + v.w * v.w;
  }
  const float rn = 1.f / sqrtf(s + 1e-12f);
  const int tile = c >> 4, row = c & 15;
#pragma unroll
  for (int g = 0; g < 4; ++g) {
    bf16x8 h8, l8;
#pragma unroll
    for (int j = 0; j < 8; ++j) {
      const float zn = z[g * 8 + j] * rn;
      const unsigned short h = bf16_rne(zn);
      h8[j] = (short)h;
      l8[j] = (short)bf16_rne(zn - bf16_to_f32(h));
    }
    char* base = Bpk + (size_t)tile * 2048 + (size_t)(g * 16 + row) * 16;
    *(bf16x8*)(base) = h8;
    *(bf16x8*)(base + 1024) = l8;
  }
}

// grid: 1024 blocks (chunk = bid>>7, token-block = bid&127), 256 thr = 4 waves.
// Each wave: TT=4 token tiles (64 tokens) vs this chunk's 64 code tiles.
__global__ __launch_bounds__(BLK, 4) void screen_kernel(
    const float* __restrict__ hs, const char* __restrict__ Bpk,
    float* __restrict__ pbest, float* __restrict__ psec,
    unsigned short* __restrict__ pidx)
{
  const int lane = threadIdx.x & 63;
  const int wave = threadIdx.x >> 6;
  const int grp = lane >> 4, row = lane & 15;
  const int chunk = blockIdx.x >> 7;
  const int tb = blockIdx.x & 127;
  const int tile0 = tb * 16 + wave * TT;

  // A fragments: lane holds token ((tile0+tt)*16+row), dims grp*8..+8, hi/lo
  bf16x8 ahi[TT], alo[TT];
#pragma unroll
  for (int tt = 0; tt < TT; ++tt) {
    const float* ap = hs + ((tile0 + tt) * 16 + row) * E_DIM + grp * 8;
    float a[8];
    ((float4*)a)[0] = ((const float4*)ap)[0];
    ((float4*)a)[1] = ((const float4*)ap)[1];
    float ps = 0.f;
#pragma unroll
    for (int j = 0; j < 8; ++j) ps = fmaf(a[j], a[j], ps);
    ps += __shfl_xor(ps, 16, 64);
    ps += __shfl_xor(ps, 32, 64);
    const float rn = 1.f / sqrtf(ps + 1e-12f);
#pragma unroll
    for (int j = 0; j < 8; ++j) {
      const float zn = a[j] * rn;
      const unsigned short h = bf16_rne(zn);
      ahi[tt][j] = (short)h;
      alo[tt][j] = (short)bf16_rne(zn - bf16_to_f32(h));
    }
  }

  float best[TT][4], sec[TT][4];
  int bct[TT][4];   // best code-tile index within chunk (exact-score carried)
#pragma unroll
  for (int tt = 0; tt < TT; ++tt)
#pragma unroll
    for (int r = 0; r < 4; ++r) { best[tt][r] = -3e38f; sec[tt][r] = -3e38f; bct[tt][r] = 0; }

  const f32x4 Z4 = {0.f, 0.f, 0.f, 0.f};
  const char* Bc = Bpk + (size_t)(chunk * TPC) * 2048 + (size_t)lane * 16;

// exact-f32 select (R2-proven): med3 keeps second-best; strict > with
// ascending ct keeps smaller index on ties (matches np.argmin)
#define PROC(CH, CL, CTV)                                                      \
  {                                                                            \
    f32x4 acc[TT];                                                             \
    _Pragma("unroll") for (int tt = 0; tt < TT; ++tt) {                        \
      acc[tt] = __builtin_amdgcn_mfma_f32_16x16x32_bf16(ahi[tt], (CH), Z4, 0, 0, 0); \
      acc[tt] = __builtin_amdgcn_mfma_f32_16x16x32_bf16(ahi[tt], (CL), acc[tt], 0, 0, 0); \
      acc[tt] = __builtin_amdgcn_mfma_f32_16x16x32_bf16(alo[tt], (CH), acc[tt], 0, 0, 0); \
    }                                                                          \
    _Pragma("unroll") for (int tt = 0; tt < TT; ++tt)                          \
    _Pragma("unroll") for (int r = 0; r < 4; ++r) {                            \
      const float d = acc[tt][r];                                              \
      sec[tt][r] = __builtin_amdgcn_fmed3f(best[tt][r], sec[tt][r], d);        \
      if (d > best[tt][r]) { best[tt][r] = d; bct[tt][r] = (CTV); }            \
    }                                                                          \
  }

  bf16x8 h0 = *(const bf16x8*)(Bc);
  bf16x8 l0 = *(const bf16x8*)(Bc + 1024);
  bf16x8 h1 = *(const bf16x8*)(Bc + 2048);
  bf16x8 l1 = *(const bf16x8*)(Bc + 3072);
  for (int ct = 0; ct < TPC; ct += 2) {
    const bf16x8 ch0 = h0, cl0 = l0, ch1 = h1, cl1 = l1;
    const char* pn = Bc + (size_t)(ct + 2) * 2048;   // pad tiles keep this safe
    h0 = *(const bf16x8*)(pn);
    l0 = *(const bf16x8*)(pn + 1024);
    h1 = *(const bf16x8*)(pn + 2048);
    l1 = *(const bf16x8*)(pn + 3072);
    PROC(ch0, cl0, ct)
    PROC(ch1, cl1, ct + 1)
  }
#undef PROC

  // cross-lane merge over the 16 code columns; smaller-index tie-break
  const int base = chunk * N_TOK;
#pragma unroll
  for (int tt = 0; tt < TT; ++tt) {
#pragma unroll
    for (int r = 0; r < 4; ++r) {
      float b = best[tt][r], s = sec[tt][r];
      int id = bct[tt][r] * 16 + row;   // code within chunk [0,1024)
#pragma unroll
      for (int w = 1; w < 16; w <<= 1) {
        const float ob = __shfl_xor(b, w, 64);
        const float os = __shfl_xor(s, w, 64);
        const int   oi = __shfl_xor(id, w, 64);
        s = fmaxf(fmaxf(s, os), fminf(b, ob));
        if (ob > b || (ob == b && oi < id)) id = oi;
        b = fmaxf(b, ob);
      }
      if (row == 0) {
        const int tok = (tile0 + tt) * 16 + grp * 4 + r;
        pbest[base + tok] = b;
        psec[base + tok] = s;
        pidx[base + tok] = (unsigned short)(chunk * 1024 + id);
      }
    }
  }
}

__global__ __launch_bounds__(BLK) void merge_kernel(
    const float* __restrict__ pbest, const float* __restrict__ psec,
    const unsigned short* __restrict__ pidx, int* __restrict__ fidx,
    int* __restrict__ flagcnt, int* __restrict__ flaglist)
{
  const int t = blockIdx.x * BLK + threadIdx.x;
  float best = -3e38f, sec = -3e38f;
  int code = 0;
#pragma unroll
  for (int ch = 0; ch < NCHUNK; ++ch) {
    const float b = pbest[ch * N_TOK + t];
    const float s = psec[ch * N_TOK + t];
    const int c = pidx[ch * N_TOK + t];
    if (b > best) { sec = fmaxf(best, s); best = b; code = c; }
    else          { sec = fmaxf(sec, b); }
  }
  fidx[t] = code;
  if (best - sec < TAU) {
    const int p = atomicAdd(flagcnt, 1);
    flaglist[p] = t;
  }
}

// exact f64 rescan (incl. the eps norm term) for near-tie tokens
__global__ __launch_bounds__(256) void recheck_kernel(
    const float* __restrict__ hs, const float* __restrict__ emb,
    const int* __restrict__ flagcnt, const int* __restrict__ flaglist,
    int* __restrict__ fidx)
{
  __shared__ double rv[256];
  __shared__ int ri[256];
  const int tid = threadIdx.x;
  const int nflag = *flagcnt;
  for (int f = blockIdx.x; f < nflag; f += gridDim.x) {
    const int t = flaglist[f];
    double z[E_DIM];
    double s = 0.0;
    const float* hp = hs + t * E_DIM;
#pragma unroll
    for (int j = 0; j < E_DIM; ++j) { z[j] = (double)hp[j]; s += z[j] * z[j]; }
    const double rz = 1.0 / sqrt(s + 1e-12);
#pragma unroll
    for (int j = 0; j < E_DIM; ++j) z[j] *= rz;

    double bobj = 1e300;
    int bidx = 0x7fffffff;
    for (int c = tid; c < K_CODES; c += 256) {
      const float* ep = emb + c * E_DIM;
      double dot = 0.0, n2 = 0.0;
#pragma unroll
      for (int j = 0; j < E_DIM; ++j) {
        const double e = (double)ep[j];
        dot = fma(e, z[j], dot);
        n2 = fma(e, e, n2);
      }
      const double obj = n2 / (n2 + 1e-12) - 2.0 * (dot / sqrt(n2 + 1e-12));
      if (obj < bobj) { bobj = obj; bidx = c; }
    }
    __syncthreads();
    rv[tid] = bobj; ri[tid] = bidx;
    __syncthreads();
    for (int sr = 128; sr > 0; sr >>= 1) {
      if (tid < sr) {
        if (rv[tid + sr] < rv[tid] ||
            (rv[tid + sr] == rv[tid] && ri[tid + sr] < ri[tid])) {
          rv[tid] = rv[tid + sr]; ri[tid] = ri[tid + sr];
        }
      }
      __syncthreads();
    }
    if (tid == 0) fidx[t] = ri[0];
    __syncthreads();
  }
}

__global__ __launch_bounds__(BLK) void finalize_kernel(
    const float* __restrict__ hs, const float* __restrict__ emb,
    const int* __restrict__ fidx, float* __restrict__ out,
    float* __restrict__ lpart)
{
  const int t = blockIdx.x * BLK + threadIdx.x;
  const int idx = fidx[t];
  const float4* ep = (const float4*)(emb + idx * E_DIM);
  const float4* hp = (const float4*)(hs + t * E_DIM);
  float4 e[8], h[8];
  float se = 0.f, sh = 0.f;
#pragma unroll
  for (int q = 0; q < 8; ++q) {
    e[q] = ep[q]; h[q] = hp[q];
    se += e[q].x * e[q].x + e[q].y * e[q].y + e[q].z * e[q].z + e[q].w * e[q].w;
    sh += h[q].x * h[q].x + h[q].y * h[q].y + h[q].z * h[q].z + h[q].w * h[q].w;
  }
  const float re = 1.f / sqrtf(se + 1e-12f);
  const float rh = 1.f / sqrtf(sh + 1e-12f);
  float4* zo = (float4*)(out + t * E_DIM);
  float err = 0.f;
#pragma unroll
  for (int q = 0; q < 8; ++q) {
    float4 zq, hn;
    zq.x = e[q].x * re; zq.y = e[q].y * re; zq.z = e[q].z * re; zq.w = e[q].w * re;
    hn.x = h[q].x * rh; hn.y = h[q].y * rh; hn.z = h[q].z * rh; hn.w = h[q].w * rh;
    float dx = zq.x - hn.x, dy = zq.y - hn.y, dz = zq.z - hn.z, dw = zq.w - hn.w;
    err += dx * dx + dy * dy + dz * dz + dw * dw;
    zo[q] = zq;
  }
  out[OUT_IDX + t] = (float)idx;
#pragma unroll
  for (int o = 32; o > 0; o >>= 1) err += __shfl_down(err, o);
  if ((threadIdx.x & 63) == 0) lpart[t >> 6] = err;
}

__global__ __launch_bounds__(256) void loss_kernel(
    const float* __restrict__ lpart, float* __restrict__ out)
{
  const int tid = threadIdx.x;
  float a = lpart[tid] + lpart[tid + 256];
#pragma unroll
  for (int o = 32; o > 0; o >>= 1) a += __shfl_down(a, o);
  __shared__ float w[4];
  if ((tid & 63) == 0) w[tid >> 6] = a;
  __syncthreads();
  if (tid == 0) {
    const float tot = (w[0] + w[1]) + (w[2] + w[3]);
    const float c = tot * (1.0f / 1048576.0f);
    out[OUT_QL] = c;
    out[OUT_EL] = c;
  }
}

extern "C" void kernel_launch(void* const* d_in, const int* in_sizes, int n_in,
                              void* d_out, int out_size, void* d_ws, size_t ws_size,
                              hipStream_t stream) {
  (void)in_sizes; (void)n_in; (void)out_size; (void)ws_size;
  const float* hs  = (const float*)d_in[0];
  const float* emb = (const float*)d_in[1];
  float* out = (float*)d_out;
  char* wsb = (char*)d_ws;

  char*           Bpk    = wsb + WSB_BPK;
  float*          pbest  = (float*)(wsb + WSB_PBEST);
  float*          psec   = (float*)(wsb + WSB_PSEC);
  unsigned short* pidx   = (unsigned short*)(wsb + WSB_PIDX);
  int*            fidx   = (int*)(wsb + WSB_FIDX);
  int*            flagcnt= (int*)(wsb + WSB_FCNT);
  int*            flist  = (int*)(wsb + WSB_FLIST);
  float*          lpart  = (float*)(wsb + WSB_LPART);

  hipMemsetAsync(flagcnt, 0, sizeof(int), stream);

  prep_emb_kernel<<<dim3(K_CODES / BLK), BLK, 0, stream>>>(emb, Bpk);
  screen_kernel<<<dim3(NCHUNK * 128), BLK, 0, stream>>>(hs, Bpk, pbest, psec, pidx);
  merge_kernel<<<dim3(N_TOK / BLK), BLK, 0, stream>>>(pbest, psec, pidx, fidx, flagcnt, flist);
  recheck_kernel<<<dim3(1024), 256, 0, stream>>>(hs, emb, flagcnt, flist, fidx);
  finalize_kernel<<<dim3(N_TOK / BLK), BLK, 0, stream>>>(hs, emb, fidx, out, lpart);
  loss_kernel<<<dim3(1), 256, 0, stream>>>(lpart, out);
}

// Round 5
// 204.217 us; speedup vs baseline: 2.5037x; 1.0019x over previous
//
#include <hip/hip_runtime.h>
#include <math.h>

#define N_TOK   32768
#define K_CODES 8192
#define E_DIM   32
#define BLK     256
#define NCHUNK  8
#define TPC     64          // code tiles per chunk (8192/8/16)
#define TT      4           // token tiles per wave
#define TAU     1e-3f       // proven in R2/R4

// d_out element offsets (float32 buffer)
#define OUT_IDX  1048576
#define OUT_QL   1081344
#define OUT_EL   1081345

// ws byte offsets
#define WSB_BPK    0         // 514 tiles * 2048 B (hi 1KB + lo 1KB interleaved)
#define WSB_PBEST  1052672   // 8*32768 f32
#define WSB_PSEC   2101248   // 8*32768 f32
#define WSB_PIDX   3149824   // 8*32768 u16
#define WSB_FIDX   3674112   // 32768 i32
#define WSB_FCNT   3805184   // 128 B
#define WSB_FLIST  3805312   // 32768 i32
#define WSB_LPART  3936384   // 512 f32

typedef __attribute__((ext_vector_type(8))) short bf16x8;
typedef __attribute__((ext_vector_type(4))) float f32x4;
typedef __attribute__((ext_vector_type(4))) double f64x4;

__device__ inline unsigned short bf16_rne(float x) {
  unsigned u = __builtin_bit_cast(unsigned, x);
  unsigned r = u + 0x7FFFu + ((u >> 16) & 1u);
  return (unsigned short)(r >> 16);
}
__device__ inline float bf16_to_f32(unsigned short h) {
  return __builtin_bit_cast(float, (unsigned)h << 16);
}

// one thread per code: normalize, bf16 hi/lo split, store MFMA-B-packed:
// tile t bytes [t*2048, +1024) = hi frag, [+1024, +2048) = lo frag;
// frag byte (g*16+coderow)*16 = code (t*16+coderow), dims g*8..+8
__global__ __launch_bounds__(BLK) void prep_emb_kernel(
    const float* __restrict__ emb, char* __restrict__ Bpk)
{
  const int c = blockIdx.x * BLK + threadIdx.x;
  float z[E_DIM];
  const float4* p = (const float4*)(emb + c * E_DIM);
  float s = 0.f;
#pragma unroll
  for (int q = 0; q < 8; ++q) {
    float4 v = p[q];
    ((float4*)z)[q] = v;
    s += v.x * v.x + v.y * v.y + v.z * v.z + v.w * v.w;
  }
  const float rn = 1.f / sqrtf(s + 1e-12f);
  const int tile = c >> 4, row = c & 15;
#pragma unroll
  for (int g = 0; g < 4; ++g) {
    bf16x8 h8, l8;
#pragma unroll
    for (int j = 0; j < 8; ++j) {
      const float zn = z[g * 8 + j] * rn;
      const unsigned short h = bf16_rne(zn);
      h8[j] = (short)h;
      l8[j] = (short)bf16_rne(zn - bf16_to_f32(h));
    }
    char* base = Bpk + (size_t)tile * 2048 + (size_t)(g * 16 + row) * 16;
    *(bf16x8*)(base) = h8;
    *(bf16x8*)(base + 1024) = l8;
  }
}

// grid: 1024 blocks (chunk = bid>>7, token-block = bid&127), 256 thr = 4 waves.
// Each wave: TT=4 token tiles (64 tokens) vs this chunk's 64 code tiles.
__global__ __launch_bounds__(BLK, 4) void screen_kernel(
    const float* __restrict__ hs, const char* __restrict__ Bpk,
    float* __restrict__ pbest, float* __restrict__ psec,
    unsigned short* __restrict__ pidx)
{
  const int lane = threadIdx.x & 63;
  const int wave = threadIdx.x >> 6;
  const int grp = lane >> 4, row = lane & 15;
  const int chunk = blockIdx.x >> 7;
  const int tb = blockIdx.x & 127;
  const int tile0 = tb * 16 + wave * TT;

  // A fragments: lane holds token ((tile0+tt)*16+row), dims grp*8..+8, hi/lo
  bf16x8 ahi[TT], alo[TT];
#pragma unroll
  for (int tt = 0; tt < TT; ++tt) {
    const float* ap = hs + ((tile0 + tt) * 16 + row) * E_DIM + grp * 8;
    float a[8];
    ((float4*)a)[0] = ((const float4*)ap)[0];
    ((float4*)a)[1] = ((const float4*)ap)[1];
    float ps = 0.f;
#pragma unroll
    for (int j = 0; j < 8; ++j) ps = fmaf(a[j], a[j], ps);
    ps += __shfl_xor(ps, 16, 64);
    ps += __shfl_xor(ps, 32, 64);
    const float rn = 1.f / sqrtf(ps + 1e-12f);
#pragma unroll
    for (int j = 0; j < 8; ++j) {
      const float zn = a[j] * rn;
      const unsigned short h = bf16_rne(zn);
      ahi[tt][j] = (short)h;
      alo[tt][j] = (short)bf16_rne(zn - bf16_to_f32(h));
    }
  }

  float best[TT][4], sec[TT][4];
  int bct[TT][4];   // best code-tile index within chunk (exact-score carried)
#pragma unroll
  for (int tt = 0; tt < TT; ++tt)
#pragma unroll
    for (int r = 0; r < 4; ++r) { best[tt][r] = -3e38f; sec[tt][r] = -3e38f; bct[tt][r] = 0; }

  const f32x4 Z4 = {0.f, 0.f, 0.f, 0.f};
  const char* Bc = Bpk + (size_t)(chunk * TPC) * 2048 + (size_t)lane * 16;

// exact-f32 select (R2-proven): med3 keeps second-best; strict > with
// ascending ct keeps smaller index on ties (matches np.argmin)
#define PROC(CH, CL, CTV)                                                      \
  {                                                                            \
    f32x4 acc[TT];                                                             \
    _Pragma("unroll") for (int tt = 0; tt < TT; ++tt) {                        \
      acc[tt] = __builtin_amdgcn_mfma_f32_16x16x32_bf16(ahi[tt], (CH), Z4, 0, 0, 0); \
      acc[tt] = __builtin_amdgcn_mfma_f32_16x16x32_bf16(ahi[tt], (CL), acc[tt], 0, 0, 0); \
      acc[tt] = __builtin_amdgcn_mfma_f32_16x16x32_bf16(alo[tt], (CH), acc[tt], 0, 0, 0); \
    }                                                                          \
    _Pragma("unroll") for (int tt = 0; tt < TT; ++tt)                          \
    _Pragma("unroll") for (int r = 0; r < 4; ++r) {                            \
      const float d = acc[tt][r];                                              \
      sec[tt][r] = __builtin_amdgcn_fmed3f(best[tt][r], sec[tt][r], d);        \
      if (d > best[tt][r]) { best[tt][r] = d; bct[tt][r] = (CTV); }            \
    }                                                                          \
  }

  bf16x8 h0 = *(const bf16x8*)(Bc);
  bf16x8 l0 = *(const bf16x8*)(Bc + 1024);
  bf16x8 h1 = *(const bf16x8*)(Bc + 2048);
  bf16x8 l1 = *(const bf16x8*)(Bc + 3072);
  for (int ct = 0; ct < TPC; ct += 2) {
    const bf16x8 ch0 = h0, cl0 = l0, ch1 = h1, cl1 = l1;
    const char* pn = Bc + (size_t)(ct + 2) * 2048;   // pad tiles keep this safe
    h0 = *(const bf16x8*)(pn);
    l0 = *(const bf16x8*)(pn + 1024);
    h1 = *(const bf16x8*)(pn + 2048);
    l1 = *(const bf16x8*)(pn + 3072);
    PROC(ch0, cl0, ct)
    PROC(ch1, cl1, ct + 1)
  }
#undef PROC

  // cross-lane merge over the 16 code columns; smaller-index tie-break
  const int base = chunk * N_TOK;
#pragma unroll
  for (int tt = 0; tt < TT; ++tt) {
#pragma unroll
    for (int r = 0; r < 4; ++r) {
      float b = best[tt][r], s = sec[tt][r];
      int id = bct[tt][r] * 16 + row;   // code within chunk [0,1024)
#pragma unroll
      for (int w = 1; w < 16; w <<= 1) {
        const float ob = __shfl_xor(b, w, 64);
        const float os = __shfl_xor(s, w, 64);
        const int   oi = __shfl_xor(id, w, 64);
        s = fmaxf(fmaxf(s, os), fminf(b, ob));
        if (ob > b || (ob == b && oi < id)) id = oi;
        b = fmaxf(b, ob);
      }
      if (row == 0) {
        const int tok = (tile0 + tt) * 16 + grp * 4 + r;
        pbest[base + tok] = b;
        psec[base + tok] = s;
        pidx[base + tok] = (unsigned short)(chunk * 1024 + id);
      }
    }
  }
}

__global__ __launch_bounds__(BLK) void merge_kernel(
    const float* __restrict__ pbest, const float* __restrict__ psec,
    const unsigned short* __restrict__ pidx, int* __restrict__ fidx,
    int* __restrict__ flagcnt, int* __restrict__ flaglist)
{
  const int t = blockIdx.x * BLK + threadIdx.x;
  float best = -3e38f, sec = -3e38f;
  int code = 0;
#pragma unroll
  for (int ch = 0; ch < NCHUNK; ++ch) {
    const float b = pbest[ch * N_TOK + t];
    const float s = psec[ch * N_TOK + t];
    const int c = pidx[ch * N_TOK + t];
    if (b > best) { sec = fmaxf(best, s); best = b; code = c; }
    else          { sec = fmaxf(sec, b); }
  }
  fidx[t] = code;
  if (best - sec < TAU) {
    const int p = atomicAdd(flagcnt, 1);
    flaglist[p] = t;
  }
}

// exact f64 rescan (incl. the eps norm term) for near-tie tokens.
// z normalized once per block -> LDS -> named f64x4 registers (no scratch).
__global__ __launch_bounds__(256) void recheck_kernel(
    const float* __restrict__ hs, const float* __restrict__ emb,
    const int* __restrict__ flagcnt, const int* __restrict__ flaglist,
    int* __restrict__ fidx)
{
  __shared__ __align__(32) double zsh[E_DIM];
  __shared__ double rv[256];
  __shared__ int ri[256];
  const int tid = threadIdx.x;
  const int nflag = *flagcnt;
  for (int f = blockIdx.x; f < nflag; f += gridDim.x) {
    const int t = flaglist[f];
    __syncthreads();   // previous iteration's zsh/ri consumers are done
    if (tid < 64) {
      const double zj = (tid < E_DIM) ? (double)hs[t * E_DIM + tid] : 0.0;
      double sq = zj * zj;
#pragma unroll
      for (int o = 16; o > 0; o >>= 1) sq += __shfl_down(sq, o, 64);
      const double s = __shfl(sq, 0, 64);
      const double rz = 1.0 / sqrt(s + 1e-12);
      if (tid < E_DIM) zsh[tid] = zj * rz;
    }
    __syncthreads();

    const f64x4 z0 = *(const f64x4*)(zsh + 0);
    const f64x4 z1 = *(const f64x4*)(zsh + 4);
    const f64x4 z2 = *(const f64x4*)(zsh + 8);
    const f64x4 z3 = *(const f64x4*)(zsh + 12);
    const f64x4 z4v = *(const f64x4*)(zsh + 16);
    const f64x4 z5 = *(const f64x4*)(zsh + 20);
    const f64x4 z6 = *(const f64x4*)(zsh + 24);
    const f64x4 z7 = *(const f64x4*)(zsh + 28);

    double bobj = 1e300;
    int bidx = 0x7fffffff;
    for (int c = tid; c < K_CODES; c += 256) {
      const float4* ep = (const float4*)(emb + c * E_DIM);
      const float4 e0 = ep[0], e1 = ep[1], e2 = ep[2], e3 = ep[3];
      const float4 e4 = ep[4], e5 = ep[5], e6 = ep[6], e7 = ep[7];
      double d0 = 0.0, d1 = 0.0, n0 = 0.0, n1 = 0.0;
#define ACC(EV, ZV, DA, NA)                                             \
      { const double ex = (double)(EV).x, ey = (double)(EV).y,          \
                     ez = (double)(EV).z, ew = (double)(EV).w;          \
        DA = fma(ex, (ZV)[0], DA); NA = fma(ex, ex, NA);                \
        DA = fma(ey, (ZV)[1], DA); NA = fma(ey, ey, NA);                \
        DA = fma(ez, (ZV)[2], DA); NA = fma(ez, ez, NA);                \
        DA = fma(ew, (ZV)[3], DA); NA = fma(ew, ew, NA); }
      ACC(e0, z0, d0, n0) ACC(e1, z1, d1, n1)
      ACC(e2, z2, d0, n0) ACC(e3, z3, d1, n1)
      ACC(e4, z4v, d0, n0) ACC(e5, z5, d1, n1)
      ACC(e6, z6, d0, n0) ACC(e7, z7, d1, n1)
#undef ACC
      const double dot = d0 + d1, n2 = n0 + n1;
      const double obj = n2 / (n2 + 1e-12) - 2.0 * (dot / sqrt(n2 + 1e-12));
      if (obj < bobj) { bobj = obj; bidx = c; }
    }
    __syncthreads();
    rv[tid] = bobj; ri[tid] = bidx;
    __syncthreads();
    for (int sr = 128; sr > 0; sr >>= 1) {
      if (tid < sr) {
        if (rv[tid + sr] < rv[tid] ||
            (rv[tid + sr] == rv[tid] && ri[tid + sr] < ri[tid])) {
          rv[tid] = rv[tid + sr]; ri[tid] = ri[tid + sr];
        }
      }
      __syncthreads();
    }
    if (tid == 0) fidx[t] = ri[0];
  }
}

__global__ __launch_bounds__(BLK) void finalize_kernel(
    const float* __restrict__ hs, const float* __restrict__ emb,
    const int* __restrict__ fidx, float* __restrict__ out,
    float* __restrict__ lpart)
{
  const int t = blockIdx.x * BLK + threadIdx.x;
  const int idx = fidx[t];
  const float4* ep = (const float4*)(emb + idx * E_DIM);
  const float4* hp = (const float4*)(hs + t * E_DIM);
  float4 e[8], h[8];
  float se = 0.f, sh = 0.f;
#pragma unroll
  for (int q = 0; q < 8; ++q) {
    e[q] = ep[q]; h[q] = hp[q];
    se += e[q].x * e[q].x + e[q].y * e[q].y + e[q].z * e[q].z + e[q].w * e[q].w;
    sh += h[q].x * h[q].x + h[q].y * h[q].y + h[q].z * h[q].z + h[q].w * h[q].w;
  }
  const float re = 1.f / sqrtf(se + 1e-12f);
  const float rh = 1.f / sqrtf(sh + 1e-12f);
  float4* zo = (float4*)(out + t * E_DIM);
  float err = 0.f;
#pragma unroll
  for (int q = 0; q < 8; ++q) {
    float4 zq, hn;
    zq.x = e[q].x * re; zq.y = e[q].y * re; zq.z = e[q].z * re; zq.w = e[q].w * re;
    hn.x = h[q].x * rh; hn.y = h[q].y * rh; hn.z = h[q].z * rh; hn.w = h[q].w * rh;
    float dx = zq.x - hn.x, dy = zq.y - hn.y, dz = zq.z - hn.z, dw = zq.w - hn.w;
    err += dx * dx + dy * dy + dz * dz + dw * dw;
    zo[q] = zq;
  }
  out[OUT_IDX + t] = (float)idx;
#pragma unroll
  for (int o = 32; o > 0; o >>= 1) err += __shfl_down(err, o);
  if ((threadIdx.x & 63) == 0) lpart[t >> 6] = err;
}

__global__ __launch_bounds__(256) void loss_kernel(
    const float* __restrict__ lpart, float* __restrict__ out)
{
  const int tid = threadIdx.x;
  float a = lpart[tid] + lpart[tid + 256];
#pragma unroll
  for (int o = 32; o > 0; o >>= 1) a += __shfl_down(a, o);
  __shared__ float w[4];
  if ((tid & 63) == 0) w[tid >> 6] = a;
  __syncthreads();
  if (tid == 0) {
    const float tot = (w[0] + w[1]) + (w[2] + w[3]);
    const float c = tot * (1.0f / 1048576.0f);
    out[OUT_QL] = c;
    out[OUT_EL] = c;
  }
}

extern "C" void kernel_launch(void* const* d_in, const int* in_sizes, int n_in,
                              void* d_out, int out_size, void* d_ws, size_t ws_size,
                              hipStream_t stream) {
  (void)in_sizes; (void)n_in; (void)out_size; (void)ws_size;
  const float* hs  = (const float*)d_in[0];
  const float* emb = (const float*)d_in[1];
  float* out = (float*)d_out;
  char* wsb = (char*)d_ws;

  char*           Bpk    = wsb + WSB_BPK;
  float*          pbest  = (float*)(wsb + WSB_PBEST);
  float*          psec   = (float*)(wsb + WSB_PSEC);
  unsigned short* pidx   = (unsigned short*)(wsb + WSB_PIDX);
  int*            fidx   = (int*)(wsb + WSB_FIDX);
  int*            flagcnt= (int*)(wsb + WSB_FCNT);
  int*            flist  = (int*)(wsb + WSB_FLIST);
  float*          lpart  = (float*)(wsb + WSB_LPART);

  hipMemsetAsync(flagcnt, 0, sizeof(int), stream);

  prep_emb_kernel<<<dim3(K_CODES / BLK), BLK, 0, stream>>>(emb, Bpk);
  screen_kernel<<<dim3(NCHUNK * 128), BLK, 0, stream>>>(hs, Bpk, pbest, psec, pidx);
  merge_kernel<<<dim3(N_TOK / BLK), BLK, 0, stream>>>(pbest, psec, pidx, fidx, flagcnt, flist);
  recheck_kernel<<<dim3(1024), 256, 0, stream>>>(hs, emb, flagcnt, flist, fidx);
  finalize_kernel<<<dim3(N_TOK / BLK), BLK, 0, stream>>>(hs, emb, fidx, out, lpart);
  loss_kernel<<<dim3(1), 256, 0, stream>>>(lpart, out);
}

// Round 6
// 204.083 us; speedup vs baseline: 2.5054x; 1.0007x over previous
//
#include <hip/hip_runtime.h>
#include <math.h>

#define N_TOK   32768
#define K_CODES 8192
#define E_DIM   32
#define BLK     256
#define NCHUNK  8
#define TPC     64          // code tiles per chunk (8192/8/16)
#define TT      4           // token tiles per wave
#define TAU     1e-3f       // proven in R2/R4/R5

// d_out element offsets (float32 buffer)
#define OUT_IDX  1048576
#define OUT_QL   1081344
#define OUT_EL   1081345

// ws byte offsets
#define WSB_BPK    0         // 514 tiles * 2048 B (hi 1KB + lo 1KB interleaved)
#define WSB_PBEST  1052672   // 8*32768 f32
#define WSB_PSEC   2101248   // 8*32768 f32
#define WSB_PIDX   3149824   // 8*32768 u16
#define WSB_FIDX   3674112   // 32768 i32
#define WSB_FCNT   3805184   // 128 B
#define WSB_FLIST  3805312   // 32768 i32
#define WSB_LPART  3936384   // 512 f32

typedef __attribute__((ext_vector_type(8))) short bf16x8;
typedef __attribute__((ext_vector_type(4))) float f32x4;
typedef __attribute__((ext_vector_type(4))) double f64x4;

__device__ inline unsigned short bf16_rne(float x) {
  unsigned u = __builtin_bit_cast(unsigned, x);
  unsigned r = u + 0x7FFFu + ((u >> 16) & 1u);
  return (unsigned short)(r >> 16);
}
__device__ inline float bf16_to_f32(unsigned short h) {
  return __builtin_bit_cast(float, (unsigned)h << 16);
}

// one thread per code: normalize, bf16 hi/lo split, store MFMA-B-packed:
// tile t bytes [t*2048, +1024) = hi frag, [+1024, +2048) = lo frag;
// frag byte (g*16+coderow)*16 = code (t*16+coderow), dims g*8..+8
__global__ __launch_bounds__(BLK) void prep_emb_kernel(
    const float* __restrict__ emb, char* __restrict__ Bpk)
{
  const int c = blockIdx.x * BLK + threadIdx.x;
  float z[E_DIM];
  const float4* p = (const float4*)(emb + c * E_DIM);
  float s = 0.f;
#pragma unroll
  for (int q = 0; q < 8; ++q) {
    float4 v = p[q];
    ((float4*)z)[q] = v;
    s += v.x * v.x + v.y * v.y + v.z * v.z + v.w * v.w;
  }
  const float rn = 1.f / sqrtf(s + 1e-12f);
  const int tile = c >> 4, row = c & 15;
#pragma unroll
  for (int g = 0; g < 4; ++g) {
    bf16x8 h8, l8;
#pragma unroll
    for (int j = 0; j < 8; ++j) {
      const float zn = z[g * 8 + j] * rn;
      const unsigned short h = bf16_rne(zn);
      h8[j] = (short)h;
      l8[j] = (short)bf16_rne(zn - bf16_to_f32(h));
    }
    char* base = Bpk + (size_t)tile * 2048 + (size_t)(g * 16 + row) * 16;
    *(bf16x8*)(base) = h8;
    *(bf16x8*)(base + 1024) = l8;
  }
}

// grid: 1024 blocks (chunk = bid>>7, token-block = bid&127), 256 thr = 4 waves.
// Each wave: TT=4 token tiles (64 tokens) vs this chunk's 64 code tiles.
__global__ __launch_bounds__(BLK, 4) void screen_kernel(
    const float* __restrict__ hs, const char* __restrict__ Bpk,
    float* __restrict__ pbest, float* __restrict__ psec,
    unsigned short* __restrict__ pidx)
{
  const int lane = threadIdx.x & 63;
  const int wave = threadIdx.x >> 6;
  const int grp = lane >> 4, row = lane & 15;
  const int chunk = blockIdx.x >> 7;
  const int tb = blockIdx.x & 127;
  const int tile0 = tb * 16 + wave * TT;

  // A fragments: lane holds token ((tile0+tt)*16+row), dims grp*8..+8, hi/lo
  bf16x8 ahi[TT], alo[TT];
#pragma unroll
  for (int tt = 0; tt < TT; ++tt) {
    const float* ap = hs + ((tile0 + tt) * 16 + row) * E_DIM + grp * 8;
    float a[8];
    ((float4*)a)[0] = ((const float4*)ap)[0];
    ((float4*)a)[1] = ((const float4*)ap)[1];
    float ps = 0.f;
#pragma unroll
    for (int j = 0; j < 8; ++j) ps = fmaf(a[j], a[j], ps);
    ps += __shfl_xor(ps, 16, 64);
    ps += __shfl_xor(ps, 32, 64);
    const float rn = 1.f / sqrtf(ps + 1e-12f);
#pragma unroll
    for (int j = 0; j < 8; ++j) {
      const float zn = a[j] * rn;
      const unsigned short h = bf16_rne(zn);
      ahi[tt][j] = (short)h;
      alo[tt][j] = (short)bf16_rne(zn - bf16_to_f32(h));
    }
  }

  float best[TT][4], sec[TT][4];
  int bct[TT][4];   // best code-tile index within chunk (exact-score carried)
#pragma unroll
  for (int tt = 0; tt < TT; ++tt)
#pragma unroll
    for (int r = 0; r < 4; ++r) { best[tt][r] = -3e38f; sec[tt][r] = -3e38f; bct[tt][r] = 0; }

  const f32x4 Z4 = {0.f, 0.f, 0.f, 0.f};
  const char* Bc = Bpk + (size_t)(chunk * TPC) * 2048 + (size_t)lane * 16;

// exact-f32 select (R2-proven): med3 keeps second-best; strict > with
// ascending ct keeps smaller index on ties (matches np.argmin)
#define PROC(CH, CL, CTV)                                                      \
  {                                                                            \
    f32x4 acc[TT];                                                             \
    _Pragma("unroll") for (int tt = 0; tt < TT; ++tt) {                        \
      acc[tt] = __builtin_amdgcn_mfma_f32_16x16x32_bf16(ahi[tt], (CH), Z4, 0, 0, 0); \
      acc[tt] = __builtin_amdgcn_mfma_f32_16x16x32_bf16(ahi[tt], (CL), acc[tt], 0, 0, 0); \
      acc[tt] = __builtin_amdgcn_mfma_f32_16x16x32_bf16(alo[tt], (CH), acc[tt], 0, 0, 0); \
    }                                                                          \
    _Pragma("unroll") for (int tt = 0; tt < TT; ++tt)                          \
    _Pragma("unroll") for (int r = 0; r < 4; ++r) {                            \
      const float d = acc[tt][r];                                              \
      sec[tt][r] = __builtin_amdgcn_fmed3f(best[tt][r], sec[tt][r], d);        \
      if (d > best[tt][r]) { best[tt][r] = d; bct[tt][r] = (CTV); }            \
    }                                                                          \
  }

  bf16x8 h0 = *(const bf16x8*)(Bc);
  bf16x8 l0 = *(const bf16x8*)(Bc + 1024);
  bf16x8 h1 = *(const bf16x8*)(Bc + 2048);
  bf16x8 l1 = *(const bf16x8*)(Bc + 3072);
  for (int ct = 0; ct < TPC; ct += 2) {
    const bf16x8 ch0 = h0, cl0 = l0, ch1 = h1, cl1 = l1;
    const char* pn = Bc + (size_t)(ct + 2) * 2048;   // pad tiles keep this safe
    h0 = *(const bf16x8*)(pn);
    l0 = *(const bf16x8*)(pn + 1024);
    h1 = *(const bf16x8*)(pn + 2048);
    l1 = *(const bf16x8*)(pn + 3072);
    PROC(ch0, cl0, ct)
    PROC(ch1, cl1, ct + 1)
  }
#undef PROC

  // cross-lane merge over the 16 code columns; smaller-index tie-break
  const int base = chunk * N_TOK;
#pragma unroll
  for (int tt = 0; tt < TT; ++tt) {
#pragma unroll
    for (int r = 0; r < 4; ++r) {
      float b = best[tt][r], s = sec[tt][r];
      int id = bct[tt][r] * 16 + row;   // code within chunk [0,1024)
#pragma unroll
      for (int w = 1; w < 16; w <<= 1) {
        const float ob = __shfl_xor(b, w, 64);
        const float os = __shfl_xor(s, w, 64);
        const int   oi = __shfl_xor(id, w, 64);
        s = fmaxf(fmaxf(s, os), fminf(b, ob));
        if (ob > b || (ob == b && oi < id)) id = oi;
        b = fmaxf(b, ob);
      }
      if (row == 0) {
        const int tok = (tile0 + tt) * 16 + grp * 4 + r;
        pbest[base + tok] = b;
        psec[base + tok] = s;
        pidx[base + tok] = (unsigned short)(chunk * 1024 + id);
      }
    }
  }
}

__global__ __launch_bounds__(BLK) void merge_kernel(
    const float* __restrict__ pbest, const float* __restrict__ psec,
    const unsigned short* __restrict__ pidx, int* __restrict__ fidx,
    int* __restrict__ flagcnt, int* __restrict__ flaglist)
{
  const int t = blockIdx.x * BLK + threadIdx.x;
  float best = -3e38f, sec = -3e38f;
  int code = 0;
#pragma unroll
  for (int ch = 0; ch < NCHUNK; ++ch) {
    const float b = pbest[ch * N_TOK + t];
    const float s = psec[ch * N_TOK + t];
    const int c = pidx[ch * N_TOK + t];
    if (b > best) { sec = fmaxf(best, s); best = b; code = c; }
    else          { sec = fmaxf(sec, b); }
  }
  fidx[t] = code;
  if (best - sec < TAU) {
    const int p = atomicAdd(flagcnt, 1);
    flaglist[p] = t;
  }
}

// exact f64 rescan (incl. the eps norm term) for near-tie tokens.
// __launch_bounds__(256, 1): allow ~512 VGPRs so z (8x f64x4) + e (8x float4)
// + f64 accumulators/div temps all stay in registers — R4/R5's 64-VGPR cap
// spilled the accumulators to scratch => ~16 dependent scratch round-trips
// per iteration => 125 us per token.
__global__ __launch_bounds__(256, 1) void recheck_kernel(
    const float* __restrict__ hs, const float* __restrict__ emb,
    const int* __restrict__ flagcnt, const int* __restrict__ flaglist,
    int* __restrict__ fidx)
{
  __shared__ __align__(32) double zsh[E_DIM];
  __shared__ double rv[256];
  __shared__ int ri[256];
  const int tid = threadIdx.x;
  const int nflag = *flagcnt;
  for (int f = blockIdx.x; f < nflag; f += gridDim.x) {
    const int t = flaglist[f];
    __syncthreads();   // previous iteration's zsh/ri consumers are done
    if (tid < 64) {
      const double zj = (tid < E_DIM) ? (double)hs[t * E_DIM + tid] : 0.0;
      double sq = zj * zj;
#pragma unroll
      for (int o = 16; o > 0; o >>= 1) sq += __shfl_down(sq, o, 64);
      const double s = __shfl(sq, 0, 64);
      const double rz = 1.0 / sqrt(s + 1e-12);
      if (tid < E_DIM) zsh[tid] = zj * rz;
    }
    __syncthreads();

    const f64x4 z0 = *(const f64x4*)(zsh + 0);
    const f64x4 z1 = *(const f64x4*)(zsh + 4);
    const f64x4 z2 = *(const f64x4*)(zsh + 8);
    const f64x4 z3 = *(const f64x4*)(zsh + 12);
    const f64x4 z4v = *(const f64x4*)(zsh + 16);
    const f64x4 z5 = *(const f64x4*)(zsh + 20);
    const f64x4 z6 = *(const f64x4*)(zsh + 24);
    const f64x4 z7 = *(const f64x4*)(zsh + 28);

    double bobj = 1e300;
    int bidx = 0x7fffffff;
#pragma unroll 2
    for (int c = tid; c < K_CODES; c += 256) {
      const float4* ep = (const float4*)(emb + c * E_DIM);
      const float4 e0 = ep[0], e1 = ep[1], e2 = ep[2], e3 = ep[3];
      const float4 e4 = ep[4], e5 = ep[5], e6 = ep[6], e7 = ep[7];
      double d0 = 0.0, d1 = 0.0, n0 = 0.0, n1 = 0.0;
#define ACC(EV, ZV, DA, NA)                                             \
      { const double ex = (double)(EV).x, ey = (double)(EV).y,          \
                     ez = (double)(EV).z, ew = (double)(EV).w;          \
        DA = fma(ex, (ZV)[0], DA); NA = fma(ex, ex, NA);                \
        DA = fma(ey, (ZV)[1], DA); NA = fma(ey, ey, NA);                \
        DA = fma(ez, (ZV)[2], DA); NA = fma(ez, ez, NA);                \
        DA = fma(ew, (ZV)[3], DA); NA = fma(ew, ew, NA); }
      ACC(e0, z0, d0, n0) ACC(e1, z1, d1, n1)
      ACC(e2, z2, d0, n0) ACC(e3, z3, d1, n1)
      ACC(e4, z4v, d0, n0) ACC(e5, z5, d1, n1)
      ACC(e6, z6, d0, n0) ACC(e7, z7, d1, n1)
#undef ACC
      const double dot = d0 + d1, n2 = n0 + n1;
      const double obj = n2 / (n2 + 1e-12) - 2.0 * (dot / sqrt(n2 + 1e-12));
      if (obj < bobj) { bobj = obj; bidx = c; }
    }
    __syncthreads();
    rv[tid] = bobj; ri[tid] = bidx;
    __syncthreads();
    for (int sr = 128; sr > 0; sr >>= 1) {
      if (tid < sr) {
        if (rv[tid + sr] < rv[tid] ||
            (rv[tid + sr] == rv[tid] && ri[tid + sr] < ri[tid])) {
          rv[tid] = rv[tid + sr]; ri[tid] = ri[tid + sr];
        }
      }
      __syncthreads();
    }
    if (tid == 0) fidx[t] = ri[0];
  }
}

__global__ __launch_bounds__(BLK) void finalize_kernel(
    const float* __restrict__ hs, const float* __restrict__ emb,
    const int* __restrict__ fidx, float* __restrict__ out,
    float* __restrict__ lpart)
{
  const int t = blockIdx.x * BLK + threadIdx.x;
  const int idx = fidx[t];
  const float4* ep = (const float4*)(emb + idx * E_DIM);
  const float4* hp = (const float4*)(hs + t * E_DIM);
  float4 e[8], h[8];
  float se = 0.f, sh = 0.f;
#pragma unroll
  for (int q = 0; q < 8; ++q) {
    e[q] = ep[q]; h[q] = hp[q];
    se += e[q].x * e[q].x + e[q].y * e[q].y + e[q].z * e[q].z + e[q].w * e[q].w;
    sh += h[q].x * h[q].x + h[q].y * h[q].y + h[q].z * h[q].z + h[q].w * h[q].w;
  }
  const float re = 1.f / sqrtf(se + 1e-12f);
  const float rh = 1.f / sqrtf(sh + 1e-12f);
  float4* zo = (float4*)(out + t * E_DIM);
  float err = 0.f;
#pragma unroll
  for (int q = 0; q < 8; ++q) {
    float4 zq, hn;
    zq.x = e[q].x * re; zq.y = e[q].y * re; zq.z = e[q].z * re; zq.w = e[q].w * re;
    hn.x = h[q].x * rh; hn.y = h[q].y * rh; hn.z = h[q].z * rh; hn.w = h[q].w * rh;
    float dx = zq.x - hn.x, dy = zq.y - hn.y, dz = zq.z - hn.z, dw = zq.w - hn.w;
    err += dx * dx + dy * dy + dz * dz + dw * dw;
    zo[q] = zq;
  }
  out[OUT_IDX + t] = (float)idx;
#pragma unroll
  for (int o = 32; o > 0; o >>= 1) err += __shfl_down(err, o);
  if ((threadIdx.x & 63) == 0) lpart[t >> 6] = err;
}

__global__ __launch_bounds__(256) void loss_kernel(
    const float* __restrict__ lpart, float* __restrict__ out)
{
  const int tid = threadIdx.x;
  float a = lpart[tid] + lpart[tid + 256];
#pragma unroll
  for (int o = 32; o > 0; o >>= 1) a += __shfl_down(a, o);
  __shared__ float w[4];
  if ((tid & 63) == 0) w[tid >> 6] = a;
  __syncthreads();
  if (tid == 0) {
    const float tot = (w[0] + w[1]) + (w[2] + w[3]);
    const float c = tot * (1.0f / 1048576.0f);
    out[OUT_QL] = c;
    out[OUT_EL] = c;
  }
}

extern "C" void kernel_launch(void* const* d_in, const int* in_sizes, int n_in,
                              void* d_out, int out_size, void* d_ws, size_t ws_size,
                              hipStream_t stream) {
  (void)in_sizes; (void)n_in; (void)out_size; (void)ws_size;
  const float* hs  = (const float*)d_in[0];
  const float* emb = (const float*)d_in[1];
  float* out = (float*)d_out;
  char* wsb = (char*)d_ws;

  char*           Bpk    = wsb + WSB_BPK;
  float*          pbest  = (float*)(wsb + WSB_PBEST);
  float*          psec   = (float*)(wsb + WSB_PSEC);
  unsigned short* pidx   = (unsigned short*)(wsb + WSB_PIDX);
  int*            fidx   = (int*)(wsb + WSB_FIDX);
  int*            flagcnt= (int*)(wsb + WSB_FCNT);
  int*            flist  = (int*)(wsb + WSB_FLIST);
  float*          lpart  = (float*)(wsb + WSB_LPART);

  hipMemsetAsync(flagcnt, 0, sizeof(int), stream);

  prep_emb_kernel<<<dim3(K_CODES / BLK), BLK, 0, stream>>>(emb, Bpk);
  screen_kernel<<<dim3(NCHUNK * 128), BLK, 0, stream>>>(hs, Bpk, pbest, psec, pidx);
  merge_kernel<<<dim3(N_TOK / BLK), BLK, 0, stream>>>(pbest, psec, pidx, fidx, flagcnt, flist);
  recheck_kernel<<<dim3(1024), 256, 0, stream>>>(hs, emb, flagcnt, flist, fidx);
  finalize_kernel<<<dim3(N_TOK / BLK), BLK, 0, stream>>>(hs, emb, fidx, out, lpart);
  loss_kernel<<<dim3(1), 256, 0, stream>>>(lpart, out);
}

// Round 7
// 135.988 us; speedup vs baseline: 3.7599x; 1.5007x over previous
//
#include <hip/hip_runtime.h>
#include <math.h>

#define N_TOK   32768
#define K_CODES 8192
#define E_DIM   32
#define BLK     256
#define NCHUNK  8
#define TPC     64          // code tiles per chunk (8192/8/16)
#define TT      4           // token tiles per wave
#define TAU     2e-4f       // 5x margin over 2*err_max(~4e-5), exact-f32 scores
#define RG      4           // flagged tokens per recheck block

// d_out element offsets (float32 buffer)
#define OUT_IDX  1048576
#define OUT_QL   1081344
#define OUT_EL   1081345

// ws byte offsets
#define WSB_BPK    0         // 514 tiles * 2048 B (hi 1KB + lo 1KB interleaved)
#define WSB_PBEST  1052672   // 8*32768 f32 (dead after merge; rz/nsq overlay)
#define WSB_PSEC   2101248   // 8*32768 f32
#define WSB_PIDX   3149824   // 8*32768 u16
#define WSB_FIDX   3674112   // 32768 i32
#define WSB_FCNT   3805184   // 128 B
#define WSB_FLIST  3805312   // 32768 i32
#define WSB_LPART  3936384   // 512 f32

typedef __attribute__((ext_vector_type(8))) short bf16x8;
typedef __attribute__((ext_vector_type(4))) float f32x4;
typedef __attribute__((ext_vector_type(4))) double f64x4;

__device__ inline unsigned short bf16_rne(float x) {
  unsigned u = __builtin_bit_cast(unsigned, x);
  unsigned r = u + 0x7FFFu + ((u >> 16) & 1u);
  return (unsigned short)(r >> 16);
}
__device__ inline float bf16_to_f32(unsigned short h) {
  return __builtin_bit_cast(float, (unsigned)h << 16);
}

// one thread per code: normalize, bf16 hi/lo split, store MFMA-B-packed
__global__ __launch_bounds__(BLK) void prep_emb_kernel(
    const float* __restrict__ emb, char* __restrict__ Bpk)
{
  const int c = blockIdx.x * BLK + threadIdx.x;
  float z[E_DIM];
  const float4* p = (const float4*)(emb + c * E_DIM);
  float s = 0.f;
#pragma unroll
  for (int q = 0; q < 8; ++q) {
    float4 v = p[q];
    ((float4*)z)[q] = v;
    s += v.x * v.x + v.y * v.y + v.z * v.z + v.w * v.w;
  }
  const float rn = 1.f / sqrtf(s + 1e-12f);
  const int tile = c >> 4, row = c & 15;
#pragma unroll
  for (int g = 0; g < 4; ++g) {
    bf16x8 h8, l8;
#pragma unroll
    for (int j = 0; j < 8; ++j) {
      const float zn = z[g * 8 + j] * rn;
      const unsigned short h = bf16_rne(zn);
      h8[j] = (short)h;
      l8[j] = (short)bf16_rne(zn - bf16_to_f32(h));
    }
    char* base = Bpk + (size_t)tile * 2048 + (size_t)(g * 16 + row) * 16;
    *(bf16x8*)(base) = h8;
    *(bf16x8*)(base + 1024) = l8;
  }
}

// per-code f64 constants for recheck: rz = 1/sqrt(n2+eps), nsq = ||e*rz||^2
__global__ __launch_bounds__(256) void prep64_kernel(
    const float* __restrict__ emb, double* __restrict__ rza,
    double* __restrict__ nsqa)
{
  const int c = blockIdx.x * 256 + threadIdx.x;
  const float4* p = (const float4*)(emb + c * E_DIM);
  float4 v[8];
  double n2 = 0.0;
#pragma unroll
  for (int q = 0; q < 8; ++q) {
    v[q] = p[q];
    const double ex = v[q].x, ey = v[q].y, ez = v[q].z, ew = v[q].w;
    n2 = fma(ew, ew, fma(ez, ez, fma(ey, ey, fma(ex, ex, n2))));
  }
  const double rz = 1.0 / sqrt(n2 + 1e-12);
  double nsq = 0.0;
#pragma unroll
  for (int q = 0; q < 8; ++q) {
    const double ex = (double)v[q].x * rz, ey = (double)v[q].y * rz;
    const double ez = (double)v[q].z * rz, ew = (double)v[q].w * rz;
    nsq = fma(ew, ew, fma(ez, ez, fma(ey, ey, fma(ex, ex, nsq))));
  }
  rza[c] = rz;
  nsqa[c] = nsq;
}

// grid: 1024 blocks (chunk = bid>>7, token-block = bid&127), 256 thr = 4 waves.
__global__ __launch_bounds__(BLK, 4) void screen_kernel(
    const float* __restrict__ hs, const char* __restrict__ Bpk,
    float* __restrict__ pbest, float* __restrict__ psec,
    unsigned short* __restrict__ pidx)
{
  const int lane = threadIdx.x & 63;
  const int wave = threadIdx.x >> 6;
  const int grp = lane >> 4, row = lane & 15;
  const int chunk = blockIdx.x >> 7;
  const int tb = blockIdx.x & 127;
  const int tile0 = tb * 16 + wave * TT;

  bf16x8 ahi[TT], alo[TT];
#pragma unroll
  for (int tt = 0; tt < TT; ++tt) {
    const float* ap = hs + ((tile0 + tt) * 16 + row) * E_DIM + grp * 8;
    float a[8];
    ((float4*)a)[0] = ((const float4*)ap)[0];
    ((float4*)a)[1] = ((const float4*)ap)[1];
    float ps = 0.f;
#pragma unroll
    for (int j = 0; j < 8; ++j) ps = fmaf(a[j], a[j], ps);
    ps += __shfl_xor(ps, 16, 64);
    ps += __shfl_xor(ps, 32, 64);
    const float rn = 1.f / sqrtf(ps + 1e-12f);
#pragma unroll
    for (int j = 0; j < 8; ++j) {
      const float zn = a[j] * rn;
      const unsigned short h = bf16_rne(zn);
      ahi[tt][j] = (short)h;
      alo[tt][j] = (short)bf16_rne(zn - bf16_to_f32(h));
    }
  }

  float best[TT][4], sec[TT][4];
  int bct[TT][4];
#pragma unroll
  for (int tt = 0; tt < TT; ++tt)
#pragma unroll
    for (int r = 0; r < 4; ++r) { best[tt][r] = -3e38f; sec[tt][r] = -3e38f; bct[tt][r] = 0; }

  const f32x4 Z4 = {0.f, 0.f, 0.f, 0.f};
  const char* Bc = Bpk + (size_t)(chunk * TPC) * 2048 + (size_t)lane * 16;

#define PROC(CH, CL, CTV)                                                      \
  {                                                                            \
    f32x4 acc[TT];                                                             \
    _Pragma("unroll") for (int tt = 0; tt < TT; ++tt) {                        \
      acc[tt] = __builtin_amdgcn_mfma_f32_16x16x32_bf16(ahi[tt], (CH), Z4, 0, 0, 0); \
      acc[tt] = __builtin_amdgcn_mfma_f32_16x16x32_bf16(ahi[tt], (CL), acc[tt], 0, 0, 0); \
      acc[tt] = __builtin_amdgcn_mfma_f32_16x16x32_bf16(alo[tt], (CH), acc[tt], 0, 0, 0); \
    }                                                                          \
    _Pragma("unroll") for (int tt = 0; tt < TT; ++tt)                          \
    _Pragma("unroll") for (int r = 0; r < 4; ++r) {                            \
      const float d = acc[tt][r];                                              \
      sec[tt][r] = __builtin_amdgcn_fmed3f(best[tt][r], sec[tt][r], d);        \
      if (d > best[tt][r]) { best[tt][r] = d; bct[tt][r] = (CTV); }            \
    }                                                                          \
  }

  bf16x8 h0 = *(const bf16x8*)(Bc);
  bf16x8 l0 = *(const bf16x8*)(Bc + 1024);
  bf16x8 h1 = *(const bf16x8*)(Bc + 2048);
  bf16x8 l1 = *(const bf16x8*)(Bc + 3072);
  for (int ct = 0; ct < TPC; ct += 2) {
    const bf16x8 ch0 = h0, cl0 = l0, ch1 = h1, cl1 = l1;
    const char* pn = Bc + (size_t)(ct + 2) * 2048;
    h0 = *(const bf16x8*)(pn);
    l0 = *(const bf16x8*)(pn + 1024);
    h1 = *(const bf16x8*)(pn + 2048);
    l1 = *(const bf16x8*)(pn + 3072);
    PROC(ch0, cl0, ct)
    PROC(ch1, cl1, ct + 1)
  }
#undef PROC

  const int base = chunk * N_TOK;
#pragma unroll
  for (int tt = 0; tt < TT; ++tt) {
#pragma unroll
    for (int r = 0; r < 4; ++r) {
      float b = best[tt][r], s = sec[tt][r];
      int id = bct[tt][r] * 16 + row;
#pragma unroll
      for (int w = 1; w < 16; w <<= 1) {
        const float ob = __shfl_xor(b, w, 64);
        const float os = __shfl_xor(s, w, 64);
        const int   oi = __shfl_xor(id, w, 64);
        s = fmaxf(fmaxf(s, os), fminf(b, ob));
        if (ob > b || (ob == b && oi < id)) id = oi;
        b = fmaxf(b, ob);
      }
      if (row == 0) {
        const int tok = (tile0 + tt) * 16 + grp * 4 + r;
        pbest[base + tok] = b;
        psec[base + tok] = s;
        pidx[base + tok] = (unsigned short)(chunk * 1024 + id);
      }
    }
  }
}

__global__ __launch_bounds__(BLK) void merge_kernel(
    const float* __restrict__ pbest, const float* __restrict__ psec,
    const unsigned short* __restrict__ pidx, int* __restrict__ fidx,
    int* __restrict__ flagcnt, int* __restrict__ flaglist)
{
  const int t = blockIdx.x * BLK + threadIdx.x;
  float best = -3e38f, sec = -3e38f;
  int code = 0;
#pragma unroll
  for (int ch = 0; ch < NCHUNK; ++ch) {
    const float b = pbest[ch * N_TOK + t];
    const float s = psec[ch * N_TOK + t];
    const int c = pidx[ch * N_TOK + t];
    if (b > best) { sec = fmaxf(best, s); best = b; code = c; }
    else          { sec = fmaxf(sec, b); }
  }
  fidx[t] = code;
  if (best - sec < TAU) {
    const int p = atomicAdd(flagcnt, 1);
    flaglist[p] = t;
  }
}

// exact f64 rescan for flagged tokens, RG tokens per block.
// No div/sqrt in the hot loop (rz/nsq precomputed); emb read amortized x RG.
__global__ __launch_bounds__(256, 1) void recheck_kernel(
    const float* __restrict__ hs, const float* __restrict__ emb,
    const double* __restrict__ rza, const double* __restrict__ nsqa,
    const int* __restrict__ flagcnt, const int* __restrict__ flaglist,
    int* __restrict__ fidx)
{
  __shared__ __align__(16) double zsh[RG][E_DIM];
  __shared__ int tsh[RG];
  __shared__ double rvW[RG][4];
  __shared__ int riW[RG][4];
  const int tid = threadIdx.x;
  const int lane = tid & 63, wv = tid >> 6;
  const int nflag = *flagcnt;
  for (int base = blockIdx.x * RG; base < nflag; base += gridDim.x * RG) {
    __syncthreads();   // protect previous iteration's zsh/tsh/rvW readers
    if (tid < 128) {
      const int g = tid >> 5, j = tid & 31;
      const bool act = (base + g) < nflag;
      const int t = act ? flaglist[base + g] : -1;
      if (j == 0) tsh[g] = t;
      const double zj = act ? (double)hs[t * E_DIM + j] : 0.0;
      double sq = zj * zj;
#pragma unroll
      for (int o = 16; o > 0; o >>= 1) sq += __shfl_xor(sq, o, 32);
      const double rzt = 1.0 / sqrt(sq + 1e-12);
      zsh[g][j] = zj * rzt;
    }
    __syncthreads();

    double bobj[RG];
    int bidx[RG];
#pragma unroll
    for (int g = 0; g < RG; ++g) { bobj[g] = 1e300; bidx[g] = 0x7fffffff; }

    for (int c = tid; c < K_CODES; c += 256) {
      const float4* ep = (const float4*)(emb + c * E_DIM);
      f64x4 e64[8];
#pragma unroll
      for (int q = 0; q < 8; ++q) {
        const float4 v = ep[q];
        e64[q][0] = (double)v.x; e64[q][1] = (double)v.y;
        e64[q][2] = (double)v.z; e64[q][3] = (double)v.w;
      }
      const double rzc = rza[c], nsqc = nsqa[c];
#pragma unroll
      for (int g = 0; g < RG; ++g) {
        double d0 = 0.0, d1 = 0.0;
#pragma unroll
        for (int q = 0; q < 8; q += 2) {
#pragma unroll
          for (int x = 0; x < 4; ++x) {
            d0 = fma(e64[q][x],     zsh[g][q * 4 + x],       d0);
            d1 = fma(e64[q + 1][x], zsh[g][(q + 1) * 4 + x], d1);
          }
        }
        const double obj = fma(-2.0, (d0 + d1) * rzc, nsqc);
        if (obj < bobj[g]) { bobj[g] = obj; bidx[g] = c; }  // ascending c: strict < keeps smallest
      }
    }

#pragma unroll
    for (int g = 0; g < RG; ++g) {
      double b = bobj[g]; int i = bidx[g];
#pragma unroll
      for (int o = 32; o > 0; o >>= 1) {
        const double ob = __shfl_down(b, o, 64);
        const int oi = __shfl_down(i, o, 64);
        if (ob < b || (ob == b && oi < i)) { b = ob; i = oi; }
      }
      if (lane == 0) { rvW[g][wv] = b; riW[g][wv] = i; }
    }
    __syncthreads();
    if (tid < RG) {
      const int g = tid;
      double b = rvW[g][0]; int i = riW[g][0];
#pragma unroll
      for (int w = 1; w < 4; ++w) {
        const double ob = rvW[g][w]; const int oi = riW[g][w];
        if (ob < b || (ob == b && oi < i)) { b = ob; i = oi; }
      }
      const int t = tsh[g];
      if (t >= 0) fidx[t] = i;
    }
  }
}

__global__ __launch_bounds__(BLK) void finalize_kernel(
    const float* __restrict__ hs, const float* __restrict__ emb,
    const int* __restrict__ fidx, float* __restrict__ out,
    float* __restrict__ lpart)
{
  const int t = blockIdx.x * BLK + threadIdx.x;
  const int idx = fidx[t];
  const float4* ep = (const float4*)(emb + idx * E_DIM);
  const float4* hp = (const float4*)(hs + t * E_DIM);
  float4 e[8], h[8];
  float se = 0.f, sh = 0.f;
#pragma unroll
  for (int q = 0; q < 8; ++q) {
    e[q] = ep[q]; h[q] = hp[q];
    se += e[q].x * e[q].x + e[q].y * e[q].y + e[q].z * e[q].z + e[q].w * e[q].w;
    sh += h[q].x * h[q].x + h[q].y * h[q].y + h[q].z * h[q].z + h[q].w * h[q].w;
  }
  const float re = 1.f / sqrtf(se + 1e-12f);
  const float rh = 1.f / sqrtf(sh + 1e-12f);
  float4* zo = (float4*)(out + t * E_DIM);
  float err = 0.f;
#pragma unroll
  for (int q = 0; q < 8; ++q) {
    float4 zq, hn;
    zq.x = e[q].x * re; zq.y = e[q].y * re; zq.z = e[q].z * re; zq.w = e[q].w * re;
    hn.x = h[q].x * rh; hn.y = h[q].y * rh; hn.z = h[q].z * rh; hn.w = h[q].w * rh;
    float dx = zq.x - hn.x, dy = zq.y - hn.y, dz = zq.z - hn.z, dw = zq.w - hn.w;
    err += dx * dx + dy * dy + dz * dz + dw * dw;
    zo[q] = zq;
  }
  out[OUT_IDX + t] = (float)idx;
#pragma unroll
  for (int o = 32; o > 0; o >>= 1) err += __shfl_down(err, o);
  if ((threadIdx.x & 63) == 0) lpart[t >> 6] = err;
}

__global__ __launch_bounds__(256) void loss_kernel(
    const float* __restrict__ lpart, float* __restrict__ out)
{
  const int tid = threadIdx.x;
  float a = lpart[tid] + lpart[tid + 256];
#pragma unroll
  for (int o = 32; o > 0; o >>= 1) a += __shfl_down(a, o);
  __shared__ float w[4];
  if ((tid & 63) == 0) w[tid >> 6] = a;
  __syncthreads();
  if (tid == 0) {
    const float tot = (w[0] + w[1]) + (w[2] + w[3]);
    const float c = tot * (1.0f / 1048576.0f);
    out[OUT_QL] = c;
    out[OUT_EL] = c;
  }
}

extern "C" void kernel_launch(void* const* d_in, const int* in_sizes, int n_in,
                              void* d_out, int out_size, void* d_ws, size_t ws_size,
                              hipStream_t stream) {
  (void)in_sizes; (void)n_in; (void)out_size; (void)ws_size;
  const float* hs  = (const float*)d_in[0];
  const float* emb = (const float*)d_in[1];
  float* out = (float*)d_out;
  char* wsb = (char*)d_ws;

  char*           Bpk    = wsb + WSB_BPK;
  float*          pbest  = (float*)(wsb + WSB_PBEST);
  float*          psec   = (float*)(wsb + WSB_PSEC);
  unsigned short* pidx   = (unsigned short*)(wsb + WSB_PIDX);
  int*            fidx   = (int*)(wsb + WSB_FIDX);
  int*            flagcnt= (int*)(wsb + WSB_FCNT);
  int*            flist  = (int*)(wsb + WSB_FLIST);
  float*          lpart  = (float*)(wsb + WSB_LPART);
  // rz/nsq overlay the pbest region (dead after merge; prep64 runs after merge)
  double*         rza    = (double*)(wsb + WSB_PBEST);
  double*         nsqa   = (double*)(wsb + WSB_PBEST + 65536);

  hipMemsetAsync(flagcnt, 0, sizeof(int), stream);

  prep_emb_kernel<<<dim3(K_CODES / BLK), BLK, 0, stream>>>(emb, Bpk);
  screen_kernel<<<dim3(NCHUNK * 128), BLK, 0, stream>>>(hs, Bpk, pbest, psec, pidx);
  merge_kernel<<<dim3(N_TOK / BLK), BLK, 0, stream>>>(pbest, psec, pidx, fidx, flagcnt, flist);
  prep64_kernel<<<dim3(K_CODES / 256), 256, 0, stream>>>(emb, rza, nsqa);
  recheck_kernel<<<dim3(512), 256, 0, stream>>>(hs, emb, rza, nsqa, flagcnt, flist, fidx);
  finalize_kernel<<<dim3(N_TOK / BLK), BLK, 0, stream>>>(hs, emb, fidx, out, lpart);
  loss_kernel<<<dim3(1), 256, 0, stream>>>(lpart, out);
}